// Round 4
// baseline (2250.609 us; speedup 1.0000x reference)
//
#include <hip/hip_runtime.h>
#include <hip/hip_cooperative_groups.h>
#include <math.h>

namespace cg = cooperative_groups;

// SpatialAttention: x[16,224,224,256] f32 (NHWC)
//   max/mean over C -> [B,H,W,2] -> conv7x7(2->1, SAME) -> sigmoid -> x * attn
// Single cooperative kernel, image-at-a-time so the mul-phase re-read of x
// hits the 256 MB Infinity Cache (one image = 50 MB).
#define B_ 16
#define H_ 224
#define W_ 224
#define C_ 256
#define IMGPIX (H_*W_)          // 50176
#define NBLK 1024               // 4 blocks/CU * 256 CUs; 16 waves/CU

typedef float f32x4 __attribute__((ext_vector_type(4)));

__global__ __launch_bounds__(256) void fused_kernel(const float* __restrict__ x,
                                                    const float* __restrict__ cw,   // [7,7,2,1]
                                                    const float* __restrict__ cb,
                                                    float* __restrict__ out,
                                                    float2* __restrict__ pooled) {
    cg::grid_group grid = cg::this_grid();
    const int t    = threadIdx.x;
    const int lane = t & 63;
    const int wid  = t >> 6;                    // wave in block 0..3
    const int gw   = blockIdx.x * 4 + wid;      // global wave id, 0..4095
    const int gg   = blockIdx.x * 16 + (t >> 4);// global 16-lane group id, 0..16383
    const int sub  = t & 15;

    // conv tap owned by this lane (lanes 0..48)
    float wm = 0.0f, wa = 0.0f;
    if (lane < 49) { wm = cw[lane * 2]; wa = cw[lane * 2 + 1]; }
    const float bias = cb[0];
    const int kh = lane / 7 - 3;
    const int kw = lane % 7 - 3;

    for (int b = 0; b < B_; ++b) {
        const float*  xb = x   + (size_t)b * IMGPIX * C_;
        float*        ob = out + (size_t)b * IMGPIX * C_;
        const float2* pb = pooled + (size_t)b * IMGPIX;

        // ---- phase 1: channel max/mean pool, 16 lanes per pixel ----
        for (int px = gg; px < IMGPIX; px += NBLK * 16) {
            const f32x4* p4 = (const f32x4*)(xb + (size_t)px * C_);
            float m = -INFINITY, s = 0.0f;
            #pragma unroll
            for (int j = 0; j < 4; ++j) {
                f32x4 v = p4[j * 16 + sub];     // normal load: allocate in L3
                m = fmaxf(m, fmaxf(fmaxf(v.x, v.y), fmaxf(v.z, v.w)));
                s += (v.x + v.y) + (v.z + v.w);
            }
            #pragma unroll
            for (int off = 1; off < 16; off <<= 1) {
                m = fmaxf(m, __shfl_xor(m, off));
                s += __shfl_xor(s, off);
            }
            if (sub == 0) ((float2*)pb)[px] = make_float2(m, s * (1.0f / 256.0f));
        }

        grid.sync();   // pooled(b) visible device-wide

        // ---- phase 2: conv7x7 + sigmoid + scale, one wave per pixel ----
        for (int px = gw; px < IMGPIX; px += NBLK * 4) {
            const int h = px / W_, w = px % W_;
            float acc = 0.0f;
            if (lane < 49) {
                const int hh = h + kh, ww = w + kw;
                if (hh >= 0 && hh < H_ && ww >= 0 && ww < W_) {
                    const float2 pv = pb[hh * W_ + ww];
                    acc = fmaf(pv.x, wm, pv.y * wa);
                }
            }
            #pragma unroll
            for (int off = 1; off < 64; off <<= 1) acc += __shfl_xor(acc, off);
            const float attn = 1.0f / (1.0f + expf(-(acc + bias)));

            f32x4 v = ((const f32x4*)(xb + (size_t)px * C_))[lane];  // L3 hit
            v.x *= attn; v.y *= attn; v.z *= attn; v.w *= attn;
            __builtin_nontemporal_store(v, &((f32x4*)ob)[(size_t)px * 64 + lane]);
        }
        // no sync needed here: pool(b+1) writes pooled(b+1), disjoint from pb reads
    }
}

extern "C" void kernel_launch(void* const* d_in, const int* in_sizes, int n_in,
                              void* d_out, int out_size, void* d_ws, size_t ws_size,
                              hipStream_t stream) {
    const float* x  = (const float*)d_in[0];
    const float* cw = (const float*)d_in[1];
    const float* cb = (const float*)d_in[2];
    float* out      = (float*)d_out;
    float2* pooled  = (float2*)d_ws;        // 16*50176*8 B = 6.4 MB

    void* args[] = { (void*)&x, (void*)&cw, (void*)&cb, (void*)&out, (void*)&pooled };
    hipLaunchCooperativeKernel((const void*)fused_kernel, dim3(NBLK), dim3(256),
                               args, 0, stream);
}

// Round 5
// 415.847 us; speedup vs baseline: 5.4121x; 5.4121x over previous
//
#include <hip/hip_runtime.h>
#include <math.h>

// SpatialAttention: x[16,224,224,256] f32 (NHWC)
//   max/mean over C -> [B,H,W,2] -> conv7x7(2->1, SAME) -> sigmoid -> x * attn
//
// Pipelined multi-dispatch: dispatch K_b = mul(image b-1) + pool(image b).
// Dispatch boundary = device barrier (CP-level, ~2-3us, flushes L2 not L3).
// mul's x re-read hits Infinity Cache (one image = 50 MB << 256 MB), proven
// by R4's cooperative version (FETCH == x-bytes once). 17 dispatches total.
#define B_ 16
#define H_ 224
#define W_ 224
#define C_ 256
#define IMGPIX (H_*W_)      // 50176
#define MULB 448            // 2 half-row blocks x 224 rows
#define POOLB 1568          // 32 pixels per block
#define GRID (MULB + POOLB) // 2016 blocks x 4 waves ~= device capacity

typedef float f32x4 __attribute__((ext_vector_type(4)));

__global__ __launch_bounds__(256) void step_kernel(const float* __restrict__ x,
                                                   const float* __restrict__ cw,   // [7,7,2,1]
                                                   const float* __restrict__ cb,
                                                   float* __restrict__ out,
                                                   float2* __restrict__ pooled,
                                                   int mb, int pb) {
    const int t   = threadIdx.x;
    const int bid = blockIdx.x;

    if (bid < MULB) {
        // ---------- mul role: conv7x7 + sigmoid + scale for image mb ----------
        if (mb < 0) return;
        __shared__ float2 spool[7][118];   // rows r-3..r+3, cols col0-3..col0+114
        __shared__ float2 sw2[49];
        __shared__ float  sbias;
        __shared__ float  sattn[112];

        const int row  = bid >> 1;         // 0..223
        const int col0 = (bid & 1) * 112;  // 0 or 112

        if (t < 98)  ((float*)sw2)[t] = cw[t];
        if (t == 98) sbias = cb[0];

        const float2* pbase = pooled + (size_t)mb * IMGPIX;
        for (int idx = t; idx < 7 * 118; idx += 256) {
            const int r  = idx / 118;
            const int ci = idx % 118;
            const int hh = row - 3 + r;
            const int c  = col0 - 3 + ci;
            float2 v = make_float2(0.0f, 0.0f);
            if (hh >= 0 && hh < H_ && c >= 0 && c < W_) v = pbase[hh * W_ + c];
            spool[r][ci] = v;
        }
        __syncthreads();

        if (t < 112) {
            float acc = 0.0f;
            #pragma unroll
            for (int kh = 0; kh < 7; ++kh) {
                #pragma unroll
                for (int kw = 0; kw < 7; ++kw) {
                    const float2 pv = spool[kh][t + kw];
                    const float2 wv = sw2[kh * 7 + kw];
                    acc = fmaf(pv.x, wv.x, fmaf(pv.y, wv.y, acc));
                }
            }
            sattn[t] = 1.0f / (1.0f + expf(-(acc + sbias)));
        }
        __syncthreads();

        // stream: 112 pixels * 64 f32x4 = 7168, in 28 iterations of 256
        const size_t pix0 = (size_t)mb * IMGPIX + (size_t)row * W_ + col0;
        const f32x4* xx = (const f32x4*)x   + pix0 * 64;   // L3 hits
        f32x4*       oo = (f32x4*)out + pix0 * 64;
        #pragma unroll 4
        for (int i = 0; i < 28; ++i) {
            const int idx = i * 256 + t;
            const float a = sattn[idx >> 6];
            f32x4 v = xx[idx];
            v.x *= a; v.y *= a; v.z *= a; v.w *= a;
            __builtin_nontemporal_store(v, &oo[idx]);
        }
    } else {
        // ---------- pool role: channel max/mean for image pb ----------
        if (pb < 0) return;
        const int pp  = bid - MULB;
        const int px0 = pp * 32;
        const int g   = t >> 4;            // 16-lane group 0..15
        const int sub = t & 15;
        const float*  xb  = x + (size_t)pb * IMGPIX * C_;
        float2*       pot = pooled + (size_t)pb * IMGPIX;
        #pragma unroll
        for (int pi = 0; pi < 2; ++pi) {
            const int px = px0 + pi * 16 + g;
            const f32x4* p4 = (const f32x4*)(xb + (size_t)px * C_);
            float m = -INFINITY, s = 0.0f;
            #pragma unroll
            for (int j = 0; j < 4; ++j) {
                f32x4 v = p4[j * 16 + sub];        // normal load: allocate in L3
                m = fmaxf(m, fmaxf(fmaxf(v.x, v.y), fmaxf(v.z, v.w)));
                s += (v.x + v.y) + (v.z + v.w);
            }
            #pragma unroll
            for (int off = 1; off < 16; off <<= 1) {
                m = fmaxf(m, __shfl_xor(m, off));
                s += __shfl_xor(s, off);
            }
            if (sub == 0) pot[px] = make_float2(m, s * (1.0f / 256.0f));
        }
    }
}

extern "C" void kernel_launch(void* const* d_in, const int* in_sizes, int n_in,
                              void* d_out, int out_size, void* d_ws, size_t ws_size,
                              hipStream_t stream) {
    const float* x  = (const float*)d_in[0];
    const float* cw = (const float*)d_in[1];
    const float* cb = (const float*)d_in[2];
    float* out      = (float*)d_out;
    float2* pooled  = (float2*)d_ws;        // 16*50176*8 B = 6.4 MB

    for (int d = 0; d <= B_; ++d) {
        const int mb = d - 1;                  // mul image (-1 = none)
        const int pb = (d < B_) ? d : -1;      // pool image (-1 = none)
        step_kernel<<<GRID, 256, 0, stream>>>(x, cw, cb, out, pooled, mb, pb);
    }
}